// Round 7
// baseline (460.539 us; speedup 1.0000x reference)
//
#include <hip/hip_runtime.h>

// Problem constants
#define B_      64
#define CIN     32
#define H_      28
#define W_      28
#define OH_     24
#define OW_     24
#define COUT    128
#define NPOS    (OH_ * OW_)          // 576
#define HW_     (H_ * W_)            // 784
#define XSTRIDE (CIN * HW_)          // 25088 floats per image
#define PSTRIDE (CIN * HW_)          // f2 elements per image-pair block

// ---------------- New path: 4 images/lane, 1 tree at a time ----------------
#define BLK      192
#define NQ       16                  // bq in [0,16): images bq,+16,+32,+48
#define NLANES   (NQ * NPOS)         // 9216
#define UB       (NLANES / BLK)      // 48
#define TPB      2                   // trees per block (LDS-staged)
#define TG       (COUT / TPB)        // 64 tree groups
#define NXCD     8
#define UPX      (UB / NXCD)         // 6
// grid = UB * TG = 3072

// WS layout (new path): XPAIR f2[32*PSTRIDE] | OFFS int[COUT*36*6] | COEF float[COUT*43*64]
#define XP_BYTES   (32 * PSTRIDE * 8)        // 6422528
#define OFF_BYTES  (COUT * 36 * 6 * 4)       // 110592
#define COEF_BYTES (COUT * 43 * 64 * 4)      // 1409024
#define WS_NEW     (XP_BYTES + OFF_BYTES + COEF_BYTES)   // ~7.9 MB

// ---------------- r6 fallback path constants ----------------
#define BLOCK    256
#define BHALF    32
#define NLANES6  (BHALF * NPOS)      // 18432
#define UBLOCKS6 (NLANES6 / BLOCK)   // 72
#define TPB6     2
#define NTP      64
#define TGROUPS6 (NTP / TPB6)        // 32
#define UPX6     (UBLOCKS6 / NXCD)   // 9
#define CF4_PER_TP (43 * 32)
#define OFF6_INTS  (NTP * 36 * 12)
#define WS_R6      ((OFF6_INTS + NTP * 43 * 128) * 4)    // 1519616

typedef float f2 __attribute__((ext_vector_type(2)));
typedef float f4 __attribute__((ext_vector_type(4)));
struct p2 { f2 a, b; };   // two image-pair units

__device__ __forceinline__ f2 pkfma(f2 x, f2 h, f2 l) {
    return __builtin_elementwise_fma(x, h, l);   // v_pk_fma_f32
}

__device__ __forceinline__ f2 clamp2(f2 v) {
    f2 r;
    r.x = __builtin_amdgcn_fmed3f(v.x, 0.0f, 1.0f);
    r.y = __builtin_amdgcn_fmed3f(v.y, 0.0f, 1.0f);
    return r;
}

template<int I>
__device__ __forceinline__ f2 sp(f4 q) {         // splat element I -> op_sel fold
    return __builtin_shufflevector(q, q, I, I);
}

// ---- Single-tree DFS Horner contraction, coeffs in LDS (uniform broadcast).
// RecT<2> fuses two leaf records into one ds_read_b128 (a0 even there).
template<int M>
struct RecT {
    static __device__ __forceinline__ p2 go(const float* __restrict__ C, int a0,
                                            const p2* xs) {
        p2 lo = RecT<M - 1>::go(C, a0, xs);
        p2 hi = RecT<M - 1>::go(C, a0 + (1 << (M - 2)), xs);
        p2 r;
        r.a = pkfma(xs[6 - M].a, hi.a, lo.a);
        r.b = pkfma(xs[6 - M].b, hi.b, lo.b);
        return r;
    }
};
template<>
struct RecT<2> {
    static __device__ __forceinline__ p2 go(const float* __restrict__ C, int a0,
                                            const p2* xs) {
        f4 q = *(const f4*)(C + 2 * a0);   // {lo0,hi0,lo1,hi1}, 16B-aligned
        p2 v0, v1, r;
        v0.a = pkfma(xs[5].a, sp<1>(q), sp<0>(q));
        v0.b = pkfma(xs[5].b, sp<1>(q), sp<0>(q));
        v1.a = pkfma(xs[5].a, sp<3>(q), sp<2>(q));
        v1.b = pkfma(xs[5].b, sp<3>(q), sp<2>(q));
        r.a = pkfma(xs[4].a, v1.a, v0.a);
        r.b = pkfma(xs[4].b, v1.b, v0.b);
        return r;
    }
};

__device__ __forceinline__ p2 contractT(const float* __restrict__ C, const p2 xs[6]) {
    p2 r = RecT<6>::go(C, 0, xs);
    r.a = clamp2(r.a);
    r.b = clamp2(r.b);
    return r;
}

__global__ __launch_bounds__(BLK, 3)
void lutconv_x(const char* __restrict__ xpc,
               const int* __restrict__ OFFS,
               const float* __restrict__ COEF,
               float* __restrict__ out) {
    __shared__ float CLs[TPB * 43 * 64];   // 22016 B

    // Bijective XCD decode: 6 pos-chunks per XCD -> ~1.6MB x-slice per L2.
    const int bid = blockIdx.x;
    const int xcd = bid % NXCD;
    const int j   = bid / NXCD;          // 0..383
    const int tg  = j % TG;              // 0..63
    const int usl = j / TG;              // 0..5
    const int us  = xcd * UPX + usl;     // 0..47

    const int g   = us * BLK + threadIdx.x;    // 0..9215
    const int bq  = g / NPOS;                  // 0..15
    const int pos = g - bq * NPOS;
    const int oh  = pos / OW_;
    const int ow  = pos - oh * OW_;
    const unsigned lin   = oh * W_ + ow;
    const unsigned byteA = (bq * PSTRIDE + lin) * 8u;          // pair (bq, bq+32)
    const unsigned byteB = ((bq + 16) * PSTRIDE + lin) * 8u;   // pair (bq+16, bq+48)

    // Stage both trees' coefficient images (1376 f4).
    {
        const f4* src = (const f4*)(COEF + (size_t)tg * (TPB * 43 * 64));
        f4* dst = (f4*)CLs;
#pragma unroll
        for (int k = 0; k < 8; ++k) {
            int i = k * BLK + threadIdx.x;
            if (i < TPB * 43 * 16) dst[i] = src[i];
        }
    }
    __syncthreads();

#pragma unroll 1
    for (int tt = 0; tt < TPB; ++tt) {
        const int t = tg * TPB + tt;
        const float* Ct = CLs + tt * (43 * 64);
        const int* Ot = OFFS + t * (36 * 6);

        p2 h2[6];
#pragma unroll
        for (int j3 = 0; j3 < 6; ++j3) {
            p2 h1[6];
#pragma unroll
            for (int j1 = 0; j1 < 6; ++j1) {
                const int* oi = Ot + (j3 * 6 + j1) * 6;
                p2 xs[6];
#pragma unroll
                for (int jj = 0; jj < 6; ++jj) {
                    int o = __builtin_amdgcn_readfirstlane(oi[jj]);
                    const char* p = xpc + o;           // scalar base (s_add)
                    p2 w;
                    w.a = *(const f2*)(p + byteA);     // global_load_dwordx2 saddr
                    w.b = *(const f2*)(p + byteB);
                    xs[jj] = w;
                }
                h1[j1] = contractT(Ct + (j3 * 7 + j1) * 64, xs);
            }
            h2[j3] = contractT(Ct + (j3 * 7 + 6) * 64, h1);
        }
        p2 r = contractT(Ct + 42 * 64, h2);

        const size_t istr = (size_t)16 * COUT * NPOS;
        size_t o0 = ((size_t)bq * COUT + t) * NPOS + pos;
        out[o0]            = r.a.x;   // bq
        out[o0 + 2 * istr] = r.a.y;   // bq+32
        out[o0 + istr]     = r.b.x;   // bq+16
        out[o0 + 3 * istr] = r.b.y;   // bq+48
    }
}

// Interleave image pairs (p, p+32) as f2.
__global__ void prep_xp(const float* __restrict__ x, f2* __restrict__ xp) {
    int i = blockIdx.x * 256 + threadIdx.x;
    if (i < 32 * PSTRIDE) {
        int p = i / PSTRIDE;
        int r = i - p * PSTRIDE;
        f2 v;
        v.x = x[p * XSTRIDE + r];
        v.y = x[(p + 32) * XSTRIDE + r];
        xp[i] = v;
    }
}

// Per (tree, node): resolve maps, Mobius-transform LUT (shfl_xor butterfly),
// write coeffs in natural Horner order + byte gather offsets (x8 for f2).
__global__ void prep_cf(const int* __restrict__ map1, const float* __restrict__ lut1,
                        const int* __restrict__ map2, const float* __restrict__ lut2,
                        const int* __restrict__ map3, const float* __restrict__ lut3,
                        int* __restrict__ OFFS, float* __restrict__ COEF) {
    const int rec  = blockIdx.x % 43;
    const int t    = blockIdx.x / 43;
    const int lane = threadIdx.x;

    const float* lp;
    int node;
    if (rec == 42) {
        node = 42;
        lp = lut3 + t * 64;
    } else {
        const int j3 = rec / 7;
        const int jr = rec - 7 * j3;
        const int n2 = map3[t * 6 + j3];
        if (jr == 6) {
            node = j3 * 7 + 6;
            lp = lut2 + (t * 6 + n2) * 64;
        } else {
            const int n1 = map2[(t * 6 + n2) * 6 + jr];
            node = j3 * 7 + jr;
            lp = lut1 + (t * 36 + n1) * 64;
            if (lane < 6) {
                int m  = map1[(t * 36 + n1) * 6 + lane];
                int c  = m / 25;
                int r  = m - 25 * c;
                int kh = r / 5;
                int kw = r - 5 * kh;
                OFFS[t * 216 + (j3 * 6 + jr) * 6 + lane] =
                    (c * HW_ + kh * W_ + kw) * 8;   // byte offset into f2 block
            }
        }
    }

    float cv = lp[lane];
#pragma unroll
    for (int s = 1; s < 64; s <<= 1) {
        float o = __shfl_xor(cv, s);
        if (lane & s) cv -= o;
    }
    COEF[((size_t)t * 43 + node) * 64 + lane] = cv;
}

// ======================= r6 fallback path (proven 374 us) =======================
template<int M>
struct RecL {
    static __device__ __forceinline__ p2 go(const f4* __restrict__ C, int a0,
                                            const p2* xs) {
        p2 lo = RecL<M - 1>::go(C, a0, xs);
        p2 hi = RecL<M - 1>::go(C, a0 + (1 << (M - 2)), xs);
        p2 r;
        r.a = pkfma(xs[6 - M].a, hi.a, lo.a);
        r.b = pkfma(xs[6 - M].b, hi.b, lo.b);
        return r;
    }
};
template<>
struct RecL<1> {
    static __device__ __forceinline__ p2 go(const f4* __restrict__ C, int a0,
                                            const p2* xs) {
        f4 q = C[a0];
        f2 lo; lo.x = q.x; lo.y = q.y;
        f2 hi; hi.x = q.z; hi.y = q.w;
        p2 r;
        r.a = pkfma(xs[5].a, hi, lo);
        r.b = pkfma(xs[5].b, hi, lo);
        return r;
    }
};

__device__ __forceinline__ p2 contract2(const f4* __restrict__ C, const p2 xs[6]) {
    p2 r = RecL<6>::go(C, 0, xs);
    r.a = clamp2(r.a);
    r.b = clamp2(r.b);
    return r;
}

__global__ __launch_bounds__(BLOCK, 3)
void lutconv_l(const float* __restrict__ x,
               const int* __restrict__ OFFS,
               const f4* __restrict__ COEF,
               float* __restrict__ out) {
    __shared__ f4 CLs[CF4_PER_TP];

    const int bid = blockIdx.x;
    const int xcd = bid % NXCD;
    const int j   = bid / NXCD;
    const int tg  = j % TGROUPS6;
    const int us  = j / TGROUPS6;
    const int u   = xcd * UPX6 + us;

    const int g   = u * BLOCK + threadIdx.x;
    const int b0  = g / NPOS;
    const int pos = g - b0 * NPOS;
    const int oh  = pos / OW_;
    const int ow  = pos - oh * OW_;
    const unsigned lin   = oh * W_ + ow;
    const unsigned voff0 = (b0 * XSTRIDE + lin) * 4u;
    const unsigned voff1 = voff0 + BHALF * XSTRIDE * 4u;
    const char* xc = (const char*)x;

#pragma unroll 1
    for (int tpi = 0; tpi < TPB6; ++tpi) {
        const int tp = tg * TPB6 + tpi;

        if (tpi) __syncthreads();
        {
            const f4* src = COEF + (size_t)tp * CF4_PER_TP;
#pragma unroll
            for (int k = 0; k < 6; ++k) {
                int i = k * BLOCK + threadIdx.x;
                if (i < CF4_PER_TP) CLs[i] = src[i];
            }
        }
        __syncthreads();

        const int* Ot = OFFS + tp * (36 * 12);

        p2 h2[6];
#pragma unroll
        for (int j3 = 0; j3 < 6; ++j3) {
            p2 h1[6];
#pragma unroll
            for (int j1 = 0; j1 < 6; ++j1) {
                const int* oi = Ot + (j3 * 6 + j1) * 12;
                p2 xs[6];
#pragma unroll
                for (int jj = 0; jj < 6; ++jj) {
                    int o0 = __builtin_amdgcn_readfirstlane(oi[2 * jj]);
                    int o1 = __builtin_amdgcn_readfirstlane(oi[2 * jj + 1]);
                    f2 va, vb;
                    va.x = *(const float*)(xc + o0 + voff0);
                    va.y = *(const float*)(xc + o1 + voff0);
                    vb.x = *(const float*)(xc + o0 + voff1);
                    vb.y = *(const float*)(xc + o1 + voff1);
                    xs[jj].a = va;
                    xs[jj].b = vb;
                }
                h1[j1] = contract2(&CLs[(j3 * 7 + j1) * 32], xs);
            }
            h2[j3] = contract2(&CLs[(j3 * 7 + 6) * 32], h1);
        }
        p2 r = contract2(&CLs[42 * 32], h2);

        size_t ob = ((size_t)b0 * COUT + 2 * tp) * NPOS + pos;
        out[ob]        = r.a.x;
        out[ob + NPOS] = r.a.y;
        size_t ob2 = ob + (size_t)BHALF * COUT * NPOS;
        out[ob2]        = r.b.x;
        out[ob2 + NPOS] = r.b.y;
    }
}

__global__ void prep_l(const int* __restrict__ map1, const float* __restrict__ lut1,
                       const int* __restrict__ map2, const float* __restrict__ lut2,
                       const int* __restrict__ map3, const float* __restrict__ lut3,
                       int* __restrict__ OFFS, float* __restrict__ COEF) {
    const int rec  = blockIdx.x % 43;
    const int tp   = blockIdx.x / 43;
    const int lane = threadIdx.x;
    const int t0 = 2 * tp, t1 = 2 * tp + 1;

    const float* lp0;
    const float* lp1;
    int node;
    if (rec == 42) {
        node = 42;
        lp0 = lut3 + t0 * 64;
        lp1 = lut3 + t1 * 64;
    } else {
        const int j3 = rec / 7;
        const int jr = rec - 7 * j3;
        const int n20 = map3[t0 * 6 + j3];
        const int n21 = map3[t1 * 6 + j3];
        if (jr == 6) {
            node = j3 * 7 + 6;
            lp0 = lut2 + (t0 * 6 + n20) * 64;
            lp1 = lut2 + (t1 * 6 + n21) * 64;
        } else {
            const int n10 = map2[(t0 * 6 + n20) * 6 + jr];
            const int n11 = map2[(t1 * 6 + n21) * 6 + jr];
            node = j3 * 7 + jr;
            lp0 = lut1 + (t0 * 36 + n10) * 64;
            lp1 = lut1 + (t1 * 36 + n11) * 64;
            if (lane < 12) {
                int h  = lane & 1;
                int jj = lane >> 1;
                int n1 = h ? n11 : n10;
                int t  = h ? t1 : t0;
                int m  = map1[(t * 36 + n1) * 6 + jj];
                int c  = m / 25;
                int r  = m - 25 * c;
                int kh = r / 5;
                int kw = r - 5 * kh;
                OFFS[(tp * 36 + j3 * 6 + jr) * 12 + jj * 2 + h] =
                    (c * HW_ + kh * W_ + kw) * 4;
            }
        }
    }

    float c0 = lp0[lane];
    float c1 = lp1[lane];
#pragma unroll
    for (int s = 1; s < 64; s <<= 1) {
        float o0 = __shfl_xor(c0, s);
        float o1 = __shfl_xor(c1, s);
        if (lane & s) { c0 -= o0; c1 -= o1; }
    }
    float* cp = COEF + ((size_t)tp * 43 + node) * 128;
    int slot = (lane >> 1) * 4 + (lane & 1) * 2;
    cp[slot]     = c0;
    cp[slot + 1] = c1;
}

// ---- Last-resort fallback: direct evaluation (no workspace needed) ----
__device__ __forceinline__ float clamp01(float v) {
    return __builtin_amdgcn_fmed3f(v, 0.0f, 1.0f);
}

__device__ __forceinline__ float contract64s(const float* __restrict__ L,
                                             const float xs[6]) {
    float v[32];
#pragma unroll
    for (int a = 0; a < 32; ++a) {
        float b = L[2 * a];
        v[a] = fmaf(xs[5], L[2 * a + 1] - b, b);
    }
#pragma unroll
    for (int a = 0; a < 16; ++a) v[a] = fmaf(xs[4], v[2*a+1] - v[2*a], v[2*a]);
#pragma unroll
    for (int a = 0; a < 8; ++a)  v[a] = fmaf(xs[3], v[2*a+1] - v[2*a], v[2*a]);
#pragma unroll
    for (int a = 0; a < 4; ++a)  v[a] = fmaf(xs[2], v[2*a+1] - v[2*a], v[2*a]);
#pragma unroll
    for (int a = 0; a < 2; ++a)  v[a] = fmaf(xs[1], v[2*a+1] - v[2*a], v[2*a]);
    return clamp01(fmaf(xs[0], v[1] - v[0], v[0]));
}

__global__ __launch_bounds__(BLOCK, 4)
void lutconv_fb(const float* __restrict__ x,
                const int* __restrict__ map1, const float* __restrict__ lut1,
                const int* __restrict__ map2, const float* __restrict__ lut2,
                const int* __restrict__ map3, const float* __restrict__ lut3,
                float* __restrict__ out) {
    const int g   = (blockIdx.x % 144) * BLOCK + threadIdx.x;
    const int tg  = blockIdx.x / 144;
    const int b   = g / NPOS;
    const int pos = g - b * NPOS;
    const int lin = (pos / OW_) * W_ + (pos - (pos / OW_) * OW_);
    const float* xb = x + (size_t)b * XSTRIDE;

#pragma unroll 1
    for (int tt = 0; tt < 8; ++tt) {
        const int t = tg * 8 + tt;
        float h2[6];
#pragma unroll
        for (int j3 = 0; j3 < 6; ++j3) {
            int n2 = __builtin_amdgcn_readfirstlane(map3[t * 6 + j3]);
            float h1[6];
#pragma unroll
            for (int j1 = 0; j1 < 6; ++j1) {
                int n1 = __builtin_amdgcn_readfirstlane(map2[(t * 6 + n2) * 6 + j1]);
                float xs[6];
#pragma unroll
                for (int jj = 0; jj < 6; ++jj) {
                    int m = map1[(t * 36 + n1) * 6 + jj];
                    int c = m / 25, r = m - 25 * c, kh = r / 5, kw = r - 5 * kh;
                    int off = __builtin_amdgcn_readfirstlane(c * HW_ + kh * W_ + kw);
                    xs[jj] = xb[off + lin];
                }
                h1[j1] = contract64s(lut1 + (t * 36 + n1) * 64, xs);
            }
            h2[j3] = contract64s(lut2 + (t * 6 + n2) * 64, h1);
        }
        out[((size_t)b * COUT + t) * NPOS + pos] = contract64s(lut3 + t * 64, h2);
    }
}

extern "C" void kernel_launch(void* const* d_in, const int* in_sizes, int n_in,
                              void* d_out, int out_size, void* d_ws, size_t ws_size,
                              hipStream_t stream) {
    const float* x    = (const float*)d_in[0];
    const int*   map1 = (const int*)d_in[1];
    const float* lut1 = (const float*)d_in[2];
    const int*   map2 = (const int*)d_in[3];
    const float* lut2 = (const float*)d_in[4];
    const int*   map3 = (const int*)d_in[5];
    const float* lut3 = (const float*)d_in[6];
    float* out = (float*)d_out;

    if (ws_size >= (size_t)WS_NEW) {
        f2*    xp   = (f2*)d_ws;
        int*   OFFS = (int*)((char*)d_ws + XP_BYTES);
        float* COEF = (float*)((char*)d_ws + XP_BYTES + OFF_BYTES);

        prep_xp<<<(32 * PSTRIDE + 255) / 256, 256, 0, stream>>>(x, xp);
        prep_cf<<<COUT * 43, 64, 0, stream>>>(map1, lut1, map2, lut2, map3, lut3,
                                              OFFS, COEF);
        lutconv_x<<<UB * TG, BLK, 0, stream>>>((const char*)xp, OFFS, COEF, out);
    } else if (ws_size >= (size_t)WS_R6) {
        int*   OFFS = (int*)d_ws;
        float* COEF = (float*)((char*)d_ws + OFF6_INTS * 4);
        prep_l<<<NTP * 43, 64, 0, stream>>>(map1, lut1, map2, lut2, map3, lut3,
                                            OFFS, COEF);
        lutconv_l<<<UBLOCKS6 * TGROUPS6, BLOCK, 0, stream>>>(
            x, OFFS, (const f4*)COEF, out);
    } else {
        lutconv_fb<<<144 * 16, BLOCK, 0, stream>>>(
            x, map1, lut1, map2, lut2, map3, lut3, out);
    }
}